// Round 4
// baseline (218.728 us; speedup 1.0000x reference)
//
#include <hip/hip_runtime.h>
#include <math.h>

// DynamicHybridRouter via bf16-split MFMA (3-term: xh*wh + xh*wl + xl*wh).
// R4: R3 was ~75us (hidden under harness fills); prime suspect = VGPR spill at the
// forced 128 cap of launch_bounds(512,4) (R2 precedent; static live count ~116+).
// Fix: expert-halved waves (2 row-tiles x 2 expert-tiles, acc 16 VGPR) + B-frag
// prefetch one step ahead, launch_bounds(512,3) (cap ~168, no spill possible,
// expected actual ~100 -> 4 waves/EU at runtime).

#define NROWS 16384
#define DIM   2048
#define NEXP  64
#define BM    32
#define TPB   512
#define KSLICE 512
#define KSTEPS (KSLICE / 32)   // 16

typedef __attribute__((ext_vector_type(4))) float f32x4;
typedef __attribute__((ext_vector_type(8))) short bf16x8;

// ---- prologue: w [64][2048] f32 -> B-frag-ordered bf16 hi/lo in ws ----
// frag slot = ((kstep*4 + t)*64 + lane): 8 bf16 of w[e=16t+(lane&15)]
// [k = kstep*32 + (lane>>4)*8 + j].  16384 slots x 16B per array.
__global__ void wfrag_kernel(const float* __restrict__ gw,
                             unsigned short* __restrict__ wsH,
                             unsigned short* __restrict__ wsL) {
  int slot  = blockIdx.x * 256 + threadIdx.x;
  int lane  = slot & 63;
  int t     = (slot >> 6) & 3;
  int kstep = slot >> 8;
  int e  = 16 * t + (lane & 15);
  int k0 = kstep * 32 + (lane >> 4) * 8;
  const float* src = gw + (size_t)e * DIM + k0;
  bf16x8 vh, vl;
#pragma unroll
  for (int j = 0; j < 8; ++j) {
    float w = src[j];
    unsigned u = __float_as_uint(w);
    vh[j] = (short)(u >> 16);
    float hi = __uint_as_float(u & 0xffff0000u);
    float rl = w - hi;
    vl[j] = (short)(__float_as_uint(rl) >> 16);
  }
  ((bf16x8*)wsH)[slot] = vh;
  ((bf16x8*)wsL)[slot] = vl;
}

// ---- main kernel ----
__global__ __launch_bounds__(TPB, 3)
void router_mfma(const float* __restrict__ x,
                 const unsigned short* __restrict__ wsH,
                 const unsigned short* __restrict__ wsL,
                 const float* __restrict__ gb,
                 const int* __restrict__ mat,
                 float* __restrict__ out) {
  __shared__ float slab[4 * BM * NEXP];   // 4 K-slice partial slabs (32KB)
  __shared__ float p_a[BM], p_b[BM];
  __shared__ int   p_i[BM], p_j[BM];
  __shared__ int   s_flag;

  const int tid  = threadIdx.x;
  const int wave = tid >> 6;
  const int ksl  = wave >> 1;    // K-slice 0..3 (512 each)
  const int eh   = wave & 1;     // expert half: experts eh*32 .. eh*32+31
  const int lane = tid & 63;
  const int m    = lane & 15;
  const int kg   = lane >> 4;
  const int row0 = blockIdx.x * BM;

  if (tid < 64) {
    unsigned long long b = __ballot(mat[lane] == 0);
    if (lane == 0) s_flag = (b != 0ull) ? 1 : 0;
  }

  f32x4 acc[2][2];
#pragma unroll
  for (int r = 0; r < 2; ++r)
#pragma unroll
    for (int t = 0; t < 2; ++t) acc[r][t] = (f32x4)0.0f;

  // B-frag base: slot = ((kstep*4 + t)*64 + lane), kstep = ksl*16 + s, t = 2*eh + tt
  const size_t bbase = (size_t)(((ksl * KSTEPS) * 4 + 2 * eh) * 64 + lane);
  const bf16x8* bHp = (const bf16x8*)wsH + bbase;
  const bf16x8* bLp = (const bf16x8*)wsL + bbase;

  const float* xb = x + (size_t)(row0 + m) * DIM + ksl * KSLICE + kg * 8;

  // prefetch step-0 x and B
  float4 xr[2][2];
  xr[0][0] = *(const float4*)(xb);
  xr[0][1] = *(const float4*)(xb + 4);
  xr[1][0] = *(const float4*)(xb + 16 * DIM);
  xr[1][1] = *(const float4*)(xb + 16 * DIM + 4);
  bf16x8 bhc[2], blc[2];
#pragma unroll
  for (int t = 0; t < 2; ++t) {
    bhc[t] = bHp[t * 64];
    blc[t] = bLp[t * 64];
  }

#pragma unroll
  for (int s = 0; s < KSTEPS; ++s) {
    // convert current x (in regs) to hi/lo bf16 A-frags
    bf16x8 ah[2], al[2];
#pragma unroll
    for (int r = 0; r < 2; ++r) {
#pragma unroll
      for (int q = 0; q < 2; ++q) {
        float4 v = xr[r][q];
        float ff[4] = {v.x, v.y, v.z, v.w};
#pragma unroll
        for (int j = 0; j < 4; ++j) {
          unsigned u = __float_as_uint(ff[j]);
          ah[r][q * 4 + j] = (short)(u >> 16);
          float hi = __uint_as_float(u & 0xffff0000u);
          float rl = ff[j] - hi;
          al[r][q * 4 + j] = (short)(__float_as_uint(rl) >> 16);
        }
      }
    }
    // prefetch next step's x (HBM/L3) and B (L2) — consumed next iteration
    const int sn = (s + 1 < KSTEPS) ? (s + 1) : s;
    {
      const float* xn = xb + sn * 32;
      xr[0][0] = *(const float4*)(xn);
      xr[0][1] = *(const float4*)(xn + 4);
      xr[1][0] = *(const float4*)(xn + 16 * DIM);
      xr[1][1] = *(const float4*)(xn + 16 * DIM + 4);
    }
    bf16x8 bhn[2], bln[2];
#pragma unroll
    for (int t = 0; t < 2; ++t) {
      bhn[t] = bHp[(size_t)sn * 256 + t * 64];
      bln[t] = bLp[(size_t)sn * 256 + t * 64];
    }
    // 3-term MFMA with current B (prefetched last iteration)
#pragma unroll
    for (int r = 0; r < 2; ++r) {
#pragma unroll
      for (int t = 0; t < 2; ++t) {
        acc[r][t] = __builtin_amdgcn_mfma_f32_16x16x32_bf16(ah[r], bhc[t], acc[r][t], 0, 0, 0);
        acc[r][t] = __builtin_amdgcn_mfma_f32_16x16x32_bf16(ah[r], blc[t], acc[r][t], 0, 0, 0);
        acc[r][t] = __builtin_amdgcn_mfma_f32_16x16x32_bf16(al[r], bhc[t], acc[r][t], 0, 0, 0);
      }
    }
#pragma unroll
    for (int t = 0; t < 2; ++t) { bhc[t] = bhn[t]; blc[t] = bln[t]; }
  }

  // ---- partials: slab[ksl][row][expert]; C/D layout col=lane&15, row=kg*4+reg.
  // Waves with same ksl write disjoint expert columns -> single barrier.
  {
    float* sl = slab + ksl * (BM * NEXP);
#pragma unroll
    for (int r = 0; r < 2; ++r)
#pragma unroll
      for (int t = 0; t < 2; ++t)
#pragma unroll
        for (int reg = 0; reg < 4; ++reg)
          sl[(16 * r + kg * 4 + reg) * NEXP + 32 * eh + 16 * t + m] = acc[r][t][reg];
  }
  __syncthreads();

  // 4 K-slice slabs + bias -> logits in slab[0..2048)
  for (int idx = tid; idx < BM * NEXP; idx += TPB) {
    float v = slab[idx] + slab[2048 + idx] + slab[4096 + idx] + slab[6144 + idx]
            + gb[idx & (NEXP - 1)];
    slab[idx] = v;
  }
  __syncthreads();

  const int flag = s_flag;

  // per-row routing (threads 0..31; rotated scan spreads LDS banks)
  if (tid < BM) {
    const float* rowp = slab + tid * NEXP;
    if (flag == 0) {
      float m1 = -1e30f, m2 = -1e30f;
      int i1 = 0, i2 = 0;
      for (int ee = 0; ee < NEXP; ++ee) {
        int e = (ee + tid) & (NEXP - 1);
        float v = rowp[e];
        if (v > m1) { m2 = m1; i2 = i1; m1 = v; i1 = e; }
        else if (v > m2) { m2 = v; i2 = e; }
      }
      float t = expf(m2 - m1);
      float pa = 1.0f / (1.0f + t);
      p_a[tid] = pa;
      p_b[tid] = t * pa;
      p_i[tid] = i1;
      p_j[tid] = i2;
    } else {
      float mx = -1e30f;
      for (int ee = 0; ee < NEXP; ++ee)
        mx = fmaxf(mx, rowp[(ee + tid) & (NEXP - 1)]);
      float ssum = 0.0f;
      for (int ee = 0; ee < NEXP; ++ee)
        ssum += expf((rowp[(ee + tid) & (NEXP - 1)] - mx) * 0.5f);  // /T=2
      p_a[tid] = mx;
      p_b[tid] = 1.0f / ssum;
    }
  }
  __syncthreads();

  // output: 32x64 tile = 512 float4, one per thread
  {
    int q  = tid;
    int r  = q >> 4;
    int e0 = (q & 15) * 4;
    float4 v;
    if (flag == 0) {
      int i1 = p_i[r], i2 = p_j[r];
      float a = p_a[r], b = p_b[r];
      v.x = (e0 + 0 == i1) ? a : (e0 + 0 == i2) ? b : 0.0f;
      v.y = (e0 + 1 == i1) ? a : (e0 + 1 == i2) ? b : 0.0f;
      v.z = (e0 + 2 == i1) ? a : (e0 + 2 == i2) ? b : 0.0f;
      v.w = (e0 + 3 == i1) ? a : (e0 + 3 == i2) ? b : 0.0f;
    } else {
      float mx = p_a[r], inv = p_b[r];
      const float* rowp = slab + r * NEXP + e0;
      v.x = expf((rowp[0] - mx) * 0.5f) * inv;
      v.y = expf((rowp[1] - mx) * 0.5f) * inv;
      v.z = expf((rowp[2] - mx) * 0.5f) * inv;
      v.w = expf((rowp[3] - mx) * 0.5f) * inv;
    }
    *(float4*)(out + (size_t)(row0 + r) * NEXP + e0) = v;
  }
}

extern "C" void kernel_launch(void* const* d_in, const int* in_sizes, int n_in,
                              void* d_out, int out_size, void* d_ws, size_t ws_size,
                              hipStream_t stream) {
  const float* x  = (const float*)d_in[0];
  const float* gw = (const float*)d_in[1];
  const float* gb = (const float*)d_in[2];
  const int*   mt = (const int*)d_in[3];
  float* outp = (float*)d_out;
  (void)in_sizes; (void)n_in; (void)out_size; (void)ws_size;

  unsigned short* wsH = (unsigned short*)d_ws;
  unsigned short* wsL = wsH + 64 * DIM;

  wfrag_kernel<<<64, 256, 0, stream>>>(gw, wsH, wsL);
  router_mfma<<<NROWS / BM, TPB, 0, stream>>>(x, wsH, wsL, gb, mt, outp);
}